// Round 7
// baseline (342.049 us; speedup 1.0000x reference)
//
#include <hip/hip_runtime.h>
#include <hip/hip_bf16.h>
#include <cstdint>
#include <cstddef>

typedef __bf16 bf16;
typedef __attribute__((ext_vector_type(8))) __bf16 bf16x8;
typedef __attribute__((ext_vector_type(4))) float floatx4;

#define NPIX 65536   // B*H*W

__device__ inline void async_copy16(void* lds, const void* g) {
    __builtin_amdgcn_global_load_lds(
        (const __attribute__((address_space(1))) void*)g,
        (__attribute__((address_space(3))) void*)lds, 16, 0, 0);
}

// ---------------------------------------------------------------- K0: Wfull = [Wo | Wo@Wc] (bf16), bco = Wo@bc + bo (fp32)
__global__ void k_prep_w(const float* __restrict__ Wc, const float* __restrict__ bc,
                         const float* __restrict__ Wo, const float* __restrict__ bo,
                         bf16* __restrict__ Wfull, float* __restrict__ bco) {
    int blk = blockIdx.x;
    int t = threadIdx.x;          // 0..383
    if (blk < 384) {
        int o = blk;
        float acc = 0.f;
        for (int d = 0; d < 384; ++d)
            acc += Wo[o * 384 + d] * Wc[d * 384 + t];
        Wfull[(size_t)o * 768 + t]       = (bf16)Wo[o * 384 + t];
        Wfull[(size_t)o * 768 + 384 + t] = (bf16)acc;
    } else {
        int o = t;
        float acc = bo[o];
        for (int d = 0; d < 384; ++d)
            acc += Wo[o * 384 + d] * bc[d];
        bco[o] = acc;
    }
}

// ---------------------------------------------------------------- K1: convert + projections (E=2), xb row-major [pixel][384]
__global__ void k_proj(const float* __restrict__ xf, bf16* __restrict__ xb,
                       const float* __restrict__ W1h, const float* __restrict__ b1h,
                       const float* __restrict__ W1w, const float* __restrict__ b1w,
                       float* __restrict__ yh, float* __restrict__ yw) {
    int t  = threadIdx.x;
    int lg = t & 7;                 // lane within 8-lane pixel group
    int pg = t >> 3;                // pixel group in block (0..31)
    int p  = blockIdx.x * 32 + pg;  // pixel id
    int b = p >> 10, h = (p >> 5) & 31, w = p & 31;
    const float4* xp4 = (const float4*)(xf + (size_t)p * 384);
    float a0 = 0.f, a1 = 0.f, a2 = 0.f, a3 = 0.f;
#pragma unroll
    for (int j = 0; j < 6; ++j) {
        int c = j * 8 + lg;         // 8-element chunk 0..47
        float4 xa = xp4[c * 2], xcv = xp4[c * 2 + 1];
        bf16x8 v;
        v[0] = (bf16)xa.x; v[1] = (bf16)xa.y; v[2] = (bf16)xa.z; v[3] = (bf16)xa.w;
        v[4] = (bf16)xcv.x; v[5] = (bf16)xcv.y; v[6] = (bf16)xcv.z; v[7] = (bf16)xcv.w;
        *(bf16x8*)(xb + (size_t)p * 384 + c * 8) = v;
        const float4* h0 = (const float4*)(W1h + c * 8);
        const float4* h1 = (const float4*)(W1h + 384 + c * 8);
        const float4* w0 = (const float4*)(W1w + c * 8);
        const float4* w1 = (const float4*)(W1w + 384 + c * 8);
        float4 h0a = h0[0], h0b = h0[1], h1a = h1[0], h1b = h1[1];
        float4 w0a = w0[0], w0b = w0[1], w1a = w1[0], w1b = w1[1];
        a0 += xa.x*h0a.x + xa.y*h0a.y + xa.z*h0a.z + xa.w*h0a.w
            + xcv.x*h0b.x + xcv.y*h0b.y + xcv.z*h0b.z + xcv.w*h0b.w;
        a1 += xa.x*h1a.x + xa.y*h1a.y + xa.z*h1a.z + xa.w*h1a.w
            + xcv.x*h1b.x + xcv.y*h1b.y + xcv.z*h1b.z + xcv.w*h1b.w;
        a2 += xa.x*w0a.x + xa.y*w0a.y + xa.z*w0a.z + xa.w*w0a.w
            + xcv.x*w0b.x + xcv.y*w0b.y + xcv.z*w0b.z + xcv.w*w0b.w;
        a3 += xa.x*w1a.x + xa.y*w1a.y + xa.z*w1a.z + xa.w*w1a.w
            + xcv.x*w1b.x + xcv.y*w1b.y + xcv.z*w1b.z + xcv.w*w1b.w;
    }
#pragma unroll
    for (int m = 1; m < 8; m <<= 1) {
        a0 += __shfl_xor(a0, m, 64);
        a1 += __shfl_xor(a1, m, 64);
        a2 += __shfl_xor(a2, m, 64);
        a3 += __shfl_xor(a3, m, 64);
    }
    if (lg == 0) {
        yh[((b * 2 + 0) * 32 + h) * 32 + w] = a0 + b1h[0];
        yh[((b * 2 + 1) * 32 + h) * 32 + w] = a1 + b1h[1];
        yw[((b * 2 + 0) * 32 + w) * 32 + h] = a2 + b1w[0];
        yw[((b * 2 + 1) * 32 + w) * 32 + h] = a3 + b1w[1];
    }
}

// ---------------------------------------------------------------- K2: grouped mix + softmax -> attn[b][l][r1][r2] (bf16)
// Single launch covers h (blk<2048) and w (blk>=2048) variants.
__global__ void k_attn(const float* __restrict__ yh_in, const float* __restrict__ yw_in,
                       const float* __restrict__ W2h, const float* __restrict__ b2h,
                       const float* __restrict__ W2w, const float* __restrict__ b2w,
                       bf16* __restrict__ attn_h, bf16* __restrict__ attn_w) {
    int blk = blockIdx.x;                 // 2 * B*32
    const float* yproj; const float* W2; const float* b2; bf16* attn;
    if (blk < 2048) { yproj = yh_in; W2 = W2h; b2 = b2h; attn = attn_h; }
    else            { yproj = yw_in; W2 = W2w; b2 = b2w; attn = attn_w; blk -= 2048; }
    int bi = blk >> 5, r1 = blk & 31;
    int g = r1 >> 2;
    int cb = g * 8;
    int e = cb >> 5, rb = cb & 31;        // 8 consecutive rows of plane e
    int lane = threadIdx.x;               // 64
    int l = lane & 31, half = lane >> 5;
    float yv[8];
    const float* ybase = yproj + (((bi * 2 + e) * 32 + rb) * 32 + l);
#pragma unroll
    for (int c = 0; c < 8; ++c) yv[c] = ybase[c * 32];
    float z[16];
#pragma unroll
    for (int jj = 0; jj < 16; ++jj) {
        int r2 = half * 16 + jj;
        int row = r1 * 32 + r2;
        const float4* wp = (const float4*)(W2 + (size_t)row * 8);
        float4 wa = wp[0], wb = wp[1];
        z[jj] = b2[row]
              + yv[0]*wa.x + yv[1]*wa.y + yv[2]*wa.z + yv[3]*wa.w
              + yv[4]*wb.x + yv[5]*wb.y + yv[6]*wb.z + yv[7]*wb.w;
    }
    float m = -1e30f;
#pragma unroll
    for (int jj = 0; jj < 16; ++jj) m = fmaxf(m, z[jj]);
    m = fmaxf(m, __shfl_xor(m, 32, 64));
    float s = 0.f;
#pragma unroll
    for (int jj = 0; jj < 16; ++jj) { z[jj] = __expf(z[jj] - m); s += z[jj]; }
    s += __shfl_xor(s, 32, 64);
    float inv = 1.f / s;
    bf16x8 o0, o1;
#pragma unroll
    for (int jj = 0; jj < 8; ++jj) o0[jj] = (bf16)(z[jj] * inv);
#pragma unroll
    for (int jj = 0; jj < 8; ++jj) o1[jj] = (bf16)(z[8 + jj] * inv);
    bf16x8* dst = (bf16x8*)(attn + ((((size_t)bi * 32 + l) * 32 + r1) * 32 + half * 16));
    dst[0] = o0;
    dst[1] = o1;
}

// ---------------------------------------------------------------- K3: fused Yh+Yw -> T (bf16, row-major) — r0 proven version
__global__ __launch_bounds__(256) void k_mix(const bf16* __restrict__ x,
                                             const bf16* __restrict__ attn_h,
                                             const bf16* __restrict__ attn_w,
                                             bf16* __restrict__ T) {
    __shared__ bf16 Xs[1024 * 16];      // [pixel][16 cols]  32 KB
    __shared__ bf16 Ts[1024 * 16];      // Yh park           32 KB
    int n = blockIdx.x;                 // 0..1535
    int a = n >> 5, r = n & 31;
    int q = a * 8 + (r & 7);            // 0..383
    int bi = q / 6, cq = q % 6;
    int c = cq * 4 + (r >> 3);          // 0..23
    int dbase = c * 16;
    int tid = threadIdx.x;
    int wv = tid >> 6, lane = tid & 63;
    int n16 = lane & 15, quad = lane >> 4;

    // ---- stage x[bi][:, dbase:dbase+16] -> Xs (lane-linear 16B chunks)
    const char* gbase = (const char*)(x + (size_t)bi * 1024 * 384 + dbase);
#pragma unroll
    for (int it = 0; it < 8; ++it) {
        int p0 = wv * 256 + it * 32;                 // 32 pixels per inst
        const char* g = gbase + (size_t)(p0 + (lane >> 1)) * 768 + (lane & 1) * 16;
        char* l = (char*)Xs + p0 * 32 + lane * 16;
        async_copy16(l, g);
    }
    __syncthreads();

    // ---- phase 1: Yh[h,w,d] = sum_j ah[w,h,j] x[j,w,d] -> Ts
#pragma unroll
    for (int wl = 0; wl < 8; ++wl) {
        int w = wv * 8 + wl;
        const bf16* ab = attn_h + ((size_t)(bi * 32 + w) * 32) * 32;
        bf16x8 af0 = *(const bf16x8*)(ab + n16 * 32 + quad * 8);
        bf16x8 af1 = *(const bf16x8*)(ab + (16 + n16) * 32 + quad * 8);
        bf16x8 bfrag;
#pragma unroll
        for (int i = 0; i < 8; ++i) {
            int j = quad * 8 + i;
            bfrag[i] = Xs[(j * 32 + w) * 16 + n16];
        }
        floatx4 c0 = {0.f, 0.f, 0.f, 0.f}, c1 = {0.f, 0.f, 0.f, 0.f};
        c0 = __builtin_amdgcn_mfma_f32_16x16x32_bf16(af0, bfrag, c0, 0, 0, 0);
        c1 = __builtin_amdgcn_mfma_f32_16x16x32_bf16(af1, bfrag, c1, 0, 0, 0);
#pragma unroll
        for (int rr = 0; rr < 4; ++rr) {
            int h0 = quad * 4 + rr;
            Ts[(h0 * 32 + w) * 16 + n16]        = (bf16)c0[rr];
            Ts[((16 + h0) * 32 + w) * 16 + n16] = (bf16)c1[rr];
        }
    }
    __syncthreads();

    // ---- phase 2: Yw[h,w,d] = sum_j aw[h,w,j] x[h,j,d]; T = Yh + Yw
#pragma unroll
    for (int hl = 0; hl < 8; ++hl) {
        int h = wv * 8 + hl;
        const bf16* ab = attn_w + ((size_t)(bi * 32 + h) * 32) * 32;
        bf16x8 af0 = *(const bf16x8*)(ab + n16 * 32 + quad * 8);
        bf16x8 af1 = *(const bf16x8*)(ab + (16 + n16) * 32 + quad * 8);
        bf16x8 bfrag;
#pragma unroll
        for (int i = 0; i < 8; ++i) {
            int j = quad * 8 + i;
            bfrag[i] = Xs[(h * 32 + j) * 16 + n16];
        }
        floatx4 c0 = {0.f, 0.f, 0.f, 0.f}, c1 = {0.f, 0.f, 0.f, 0.f};
        c0 = __builtin_amdgcn_mfma_f32_16x16x32_bf16(af0, bfrag, c0, 0, 0, 0);
        c1 = __builtin_amdgcn_mfma_f32_16x16x32_bf16(af1, bfrag, c1, 0, 0, 0);
        bf16* Tr = T + ((size_t)(bi * 32 + h) * 32) * 384 + dbase;
#pragma unroll
        for (int rr = 0; rr < 4; ++rr) {
            int w0 = quad * 4 + rr;
            Tr[(size_t)w0 * 384 + n16] =
                (bf16)(c0[rr] + (float)Ts[(h * 32 + w0) * 16 + n16]);
            Tr[(size_t)(16 + w0) * 384 + n16] =
                (bf16)(c1[rr] + (float)Ts[(h * 32 + 16 + w0) * 16 + n16]);
        }
    }
}

// ---------------------------------------------------------------- K5: out = [T|xb] @ Wfull^T + bco   (M=65536,N=384,K=768), out fp32
// r4 winner + LDS DOUBLE-BUFFER: one barrier per K-step (13 total vs 24).
// Per step: issue loads(kt+1) -> MFMA on buf[kt&1] (hides load latency) ->
// ds_write buf[(kt+1)&1] (vmcnt drain lands here, after the MFMAs) -> barrier.
// Race-free: iter k's reads of buf[k&1] complete (lgkm drain) before its
// trailing barrier; iter k+1's writes to that buffer come after it.
#define LDP 72
__global__ __launch_bounds__(256) void k_gemm(const bf16* __restrict__ T, const bf16* __restrict__ x,
                                              const bf16* __restrict__ Wfull, const float* __restrict__ bco,
                                              float* __restrict__ out) {
    __shared__ bf16 As[2][128 * LDP];
    __shared__ bf16 Bs[2][128 * LDP];
    int bx = blockIdx.x;               // 0..1535
    int gid = (bx & 7) * 192 + (bx >> 3);
    int nt = gid % 3, pt = gid / 3;
    int obase = nt * 128;
    int pbase = pt * 128;
    int tid = threadIdx.x;
    int wv = tid >> 6, lane = tid & 63;
    int wm = wv & 1, wn = wv >> 1;
    int n16 = lane & 15, quad = lane >> 4;
    int lrow = tid >> 3;           // 0..31
    int lchunk = tid & 7;          // 0..7
    floatx4 zero = {0.f, 0.f, 0.f, 0.f};
    floatx4 acc[4][4];
#pragma unroll
    for (int i = 0; i < 4; ++i)
#pragma unroll
        for (int j = 0; j < 4; ++j) acc[i][j] = zero;

    const bf16* Bg0 = Wfull + (size_t)obase * 768;

    bf16x8 av[4], bv[4];
    auto load_tile = [&](int kt) {
        const bf16* Asrc = (kt < 6) ? (T + (size_t)pbase * 384 + kt * 64)
                                    : (x + (size_t)pbase * 384 + (kt - 6) * 64);
        const bf16* Bsrc = Bg0 + kt * 64;
#pragma unroll
        for (int s = 0; s < 4; ++s)
            av[s] = *(const bf16x8*)(Asrc + (size_t)(s * 32 + lrow) * 384 + lchunk * 8);
#pragma unroll
        for (int s = 0; s < 4; ++s)
            bv[s] = *(const bf16x8*)(Bsrc + (size_t)(s * 32 + lrow) * 768 + lchunk * 8);
    };
    auto write_tile = [&](int buf) {
#pragma unroll
        for (int s = 0; s < 4; ++s)
            *(bf16x8*)(As[buf] + (s * 32 + lrow) * LDP + lchunk * 8) = av[s];
#pragma unroll
        for (int s = 0; s < 4; ++s)
            *(bf16x8*)(Bs[buf] + (s * 32 + lrow) * LDP + lchunk * 8) = bv[s];
    };
    auto mfma_tile = [&](int buf) {
#pragma unroll
        for (int ks = 0; ks < 2; ++ks) {
            bf16x8 a[4], b[4];
#pragma unroll
            for (int i = 0; i < 4; ++i)
                a[i] = *(const bf16x8*)(As[buf] + (wm * 64 + i * 16 + n16) * LDP + ks * 32 + quad * 8);
#pragma unroll
            for (int i = 0; i < 4; ++i)
                b[i] = *(const bf16x8*)(Bs[buf] + (wn * 64 + i * 16 + n16) * LDP + ks * 32 + quad * 8);
#pragma unroll
            for (int i = 0; i < 4; ++i)
#pragma unroll
                for (int j = 0; j < 4; ++j)
                    acc[i][j] = __builtin_amdgcn_mfma_f32_16x16x32_bf16(a[i], b[j], acc[i][j], 0, 0, 0);
        }
    };

    load_tile(0);
    write_tile(0);
    __syncthreads();
    for (int kt = 0; kt < 12; kt += 2) {
        // even step: compute buf0, prep buf1
        if (kt < 11) load_tile(kt + 1);
        mfma_tile(0);
        if (kt < 11) { write_tile(1); __syncthreads(); }
        // odd step: compute buf1, prep buf0
        if (kt + 1 < 11) load_tile(kt + 2);
        mfma_tile(1);
        if (kt + 1 < 11) { write_tile(0); __syncthreads(); }
    }

    // epilogue: fp32 output
#pragma unroll
    for (int j = 0; j < 4; ++j) {
        int o = obase + wn * 64 + j * 16 + n16;
        float bcv = bco[o];
#pragma unroll
        for (int i = 0; i < 4; ++i) {
            int prow = pbase + wm * 64 + i * 16 + quad * 4;
#pragma unroll
            for (int r = 0; r < 4; ++r)
                out[(size_t)(prow + r) * 384 + o] = acc[i][j][r] + bcv;
        }
    }
}

// ---------------------------------------------------------------- launch
extern "C" void kernel_launch(void* const* d_in, const int* in_sizes, int n_in,
                              void* d_out, int out_size, void* d_ws, size_t ws_size,
                              hipStream_t stream) {
    const float* x   = (const float*)d_in[0];
    const float* Wc  = (const float*)d_in[1];
    const float* bc  = (const float*)d_in[2];
    const float* Wo  = (const float*)d_in[3];
    const float* bo  = (const float*)d_in[4];
    const float* W1h = (const float*)d_in[5];
    const float* b1h = (const float*)d_in[6];
    const float* W2h = (const float*)d_in[7];
    const float* b2h = (const float*)d_in[8];
    const float* W1w = (const float*)d_in[9];
    const float* b1w = (const float*)d_in[10];
    const float* W2w = (const float*)d_in[11];
    const float* b2w = (const float*)d_in[12];
    float* out = (float*)d_out;

    char* ws = (char*)d_ws;
    size_t off = 0;
    auto alloc = [&](size_t bytes) {
        void* p = ws + off;
        off = (off + bytes + 255) & ~(size_t)255;
        return p;
    };
    bf16*  xb     = (bf16*)alloc((size_t)NPIX * 384 * 2);  // bf16 copy of x, row-major
    float* yh     = (float*)alloc((size_t)131072 * 4);     // [B][2][32][32]
    float* yw     = (float*)alloc((size_t)131072 * 4);
    bf16*  attn_h = (bf16*)alloc((size_t)2097152 * 2);     // [B][W][H][H]
    bf16*  attn_w = (bf16*)alloc((size_t)2097152 * 2);     // [B][H][W][W]
    bf16*  T      = (bf16*)alloc((size_t)NPIX * 384 * 2);  // Yh+Yw, row-major
    bf16*  Wfull  = (bf16*)alloc((size_t)384 * 768 * 2);   // [Wo | Wo@Wc]
    float* bco    = (float*)alloc((size_t)384 * 4);

    hipLaunchKernelGGL(k_prep_w, dim3(385), dim3(384), 0, stream, Wc, bc, Wo, bo, Wfull, bco);
    hipLaunchKernelGGL(k_proj, dim3(2048), dim3(256), 0, stream, x, xb, W1h, b1h, W1w, b1w, yh, yw);
    hipLaunchKernelGGL(k_attn, dim3(4096), dim3(64), 0, stream, yh, yw, W2h, b2h, W2w, b2w, attn_h, attn_w);
    hipLaunchKernelGGL(k_mix, dim3(1536), dim3(256), 0, stream, xb, attn_h, attn_w, T);
    hipLaunchKernelGGL(k_gemm, dim3(1536), dim3(256), 0, stream, T, xb, Wfull, bco, out);
}

// Round 8
// 330.313 us; speedup vs baseline: 1.0355x; 1.0355x over previous
//
#include <hip/hip_runtime.h>
#include <hip/hip_bf16.h>
#include <cstdint>
#include <cstddef>

typedef __bf16 bf16;
typedef __attribute__((ext_vector_type(8))) __bf16 bf16x8;
typedef __attribute__((ext_vector_type(4))) float floatx4;

#define NPIX 65536   // B*H*W

__device__ inline void async_copy16(void* lds, const void* g) {
    __builtin_amdgcn_global_load_lds(
        (const __attribute__((address_space(1))) void*)g,
        (__attribute__((address_space(3))) void*)lds, 16, 0, 0);
}

// ---------------------------------------------------------------- K0: Wfull = [Wo | Wo@Wc] (bf16), bco = Wo@bc + bo (fp32)
__global__ void k_prep_w(const float* __restrict__ Wc, const float* __restrict__ bc,
                         const float* __restrict__ Wo, const float* __restrict__ bo,
                         bf16* __restrict__ Wfull, float* __restrict__ bco) {
    int blk = blockIdx.x;
    int t = threadIdx.x;          // 0..383
    if (blk < 384) {
        int o = blk;
        float acc = 0.f;
        for (int d = 0; d < 384; ++d)
            acc += Wo[o * 384 + d] * Wc[d * 384 + t];
        Wfull[(size_t)o * 768 + t]       = (bf16)Wo[o * 384 + t];
        Wfull[(size_t)o * 768 + 384 + t] = (bf16)acc;
    } else {
        int o = t;
        float acc = bo[o];
        for (int d = 0; d < 384; ++d)
            acc += Wo[o * 384 + d] * bc[d];
        bco[o] = acc;
    }
}

// ---------------------------------------------------------------- K1: convert + projections (E=2), xb row-major [pixel][384]
// 4 pixels per 8-lane group, j-loop outermost: the 8 W-float4s per j are
// loaded ONCE and reused across 4 pixels (per-pixel VMEM insts 66 -> ~30).
__global__ __launch_bounds__(256) void k_proj(const float* __restrict__ xf, bf16* __restrict__ xb,
                       const float* __restrict__ W1h, const float* __restrict__ b1h,
                       const float* __restrict__ W1w, const float* __restrict__ b1w,
                       float* __restrict__ yh, float* __restrict__ yw) {
    int t  = threadIdx.x;
    int lg = t & 7;                  // lane within 8-lane pixel group
    int pg = t >> 3;                 // group in block (0..31)
    int p0 = blockIdx.x * 128 + pg * 4;  // first of 4 pixels
    const float4* xp[4];
#pragma unroll
    for (int r = 0; r < 4; ++r)
        xp[r] = (const float4*)(xf + (size_t)(p0 + r) * 384);
    float acc[4][4];
#pragma unroll
    for (int r = 0; r < 4; ++r)
#pragma unroll
        for (int k = 0; k < 4; ++k) acc[r][k] = 0.f;
#pragma unroll
    for (int j = 0; j < 6; ++j) {
        int c = j * 8 + lg;          // 8-element chunk 0..47
        const float4* h0 = (const float4*)(W1h + c * 8);
        const float4* h1 = (const float4*)(W1h + 384 + c * 8);
        const float4* w0 = (const float4*)(W1w + c * 8);
        const float4* w1 = (const float4*)(W1w + 384 + c * 8);
        float4 h0a = h0[0], h0b = h0[1], h1a = h1[0], h1b = h1[1];
        float4 w0a = w0[0], w0b = w0[1], w1a = w1[0], w1b = w1[1];
#pragma unroll
        for (int r = 0; r < 4; ++r) {
            float4 xa = xp[r][c * 2], xcv = xp[r][c * 2 + 1];
            bf16x8 v;
            v[0] = (bf16)xa.x; v[1] = (bf16)xa.y; v[2] = (bf16)xa.z; v[3] = (bf16)xa.w;
            v[4] = (bf16)xcv.x; v[5] = (bf16)xcv.y; v[6] = (bf16)xcv.z; v[7] = (bf16)xcv.w;
            *(bf16x8*)(xb + (size_t)(p0 + r) * 384 + c * 8) = v;
            acc[r][0] += xa.x*h0a.x + xa.y*h0a.y + xa.z*h0a.z + xa.w*h0a.w
                       + xcv.x*h0b.x + xcv.y*h0b.y + xcv.z*h0b.z + xcv.w*h0b.w;
            acc[r][1] += xa.x*h1a.x + xa.y*h1a.y + xa.z*h1a.z + xa.w*h1a.w
                       + xcv.x*h1b.x + xcv.y*h1b.y + xcv.z*h1b.z + xcv.w*h1b.w;
            acc[r][2] += xa.x*w0a.x + xa.y*w0a.y + xa.z*w0a.z + xa.w*w0a.w
                       + xcv.x*w0b.x + xcv.y*w0b.y + xcv.z*w0b.z + xcv.w*w0b.w;
            acc[r][3] += xa.x*w1a.x + xa.y*w1a.y + xa.z*w1a.z + xa.w*w1a.w
                       + xcv.x*w1b.x + xcv.y*w1b.y + xcv.z*w1b.z + xcv.w*w1b.w;
        }
    }
#pragma unroll
    for (int r = 0; r < 4; ++r) {
#pragma unroll
        for (int m = 1; m < 8; m <<= 1) {
            acc[r][0] += __shfl_xor(acc[r][0], m, 64);
            acc[r][1] += __shfl_xor(acc[r][1], m, 64);
            acc[r][2] += __shfl_xor(acc[r][2], m, 64);
            acc[r][3] += __shfl_xor(acc[r][3], m, 64);
        }
        if (lg == 0) {
            int p = p0 + r;
            int b = p >> 10, h = (p >> 5) & 31, w = p & 31;
            yh[((b * 2 + 0) * 32 + h) * 32 + w] = acc[r][0] + b1h[0];
            yh[((b * 2 + 1) * 32 + h) * 32 + w] = acc[r][1] + b1h[1];
            yw[((b * 2 + 0) * 32 + w) * 32 + h] = acc[r][2] + b1w[0];
            yw[((b * 2 + 1) * 32 + w) * 32 + h] = acc[r][3] + b1w[1];
        }
    }
}

// ---------------------------------------------------------------- K2: grouped mix + softmax -> attn[b][l][r1][r2] (bf16)
// 256-thread blocks, 4 waves each handling one (variant, bi, r1) unit.
__global__ __launch_bounds__(256) void k_attn(const float* __restrict__ yh_in, const float* __restrict__ yw_in,
                       const float* __restrict__ W2h, const float* __restrict__ b2h,
                       const float* __restrict__ W2w, const float* __restrict__ b2w,
                       bf16* __restrict__ attn_h, bf16* __restrict__ attn_w) {
    int blk = blockIdx.x * 4 + (threadIdx.x >> 6);   // 0..4095
    const float* yproj; const float* W2; const float* b2; bf16* attn;
    if (blk < 2048) { yproj = yh_in; W2 = W2h; b2 = b2h; attn = attn_h; }
    else            { yproj = yw_in; W2 = W2w; b2 = b2w; attn = attn_w; blk -= 2048; }
    int bi = blk >> 5, r1 = blk & 31;
    int g = r1 >> 2;
    int cb = g * 8;
    int e = cb >> 5, rb = cb & 31;        // 8 consecutive rows of plane e
    int lane = threadIdx.x & 63;
    int l = lane & 31, half = lane >> 5;
    float yv[8];
    const float* ybase = yproj + (((bi * 2 + e) * 32 + rb) * 32 + l);
#pragma unroll
    for (int c = 0; c < 8; ++c) yv[c] = ybase[c * 32];
    float z[16];
#pragma unroll
    for (int jj = 0; jj < 16; ++jj) {
        int r2 = half * 16 + jj;
        int row = r1 * 32 + r2;
        const float4* wp = (const float4*)(W2 + (size_t)row * 8);
        float4 wa = wp[0], wb = wp[1];
        z[jj] = b2[row]
              + yv[0]*wa.x + yv[1]*wa.y + yv[2]*wa.z + yv[3]*wa.w
              + yv[4]*wb.x + yv[5]*wb.y + yv[6]*wb.z + yv[7]*wb.w;
    }
    float m = -1e30f;
#pragma unroll
    for (int jj = 0; jj < 16; ++jj) m = fmaxf(m, z[jj]);
    m = fmaxf(m, __shfl_xor(m, 32, 64));
    float s = 0.f;
#pragma unroll
    for (int jj = 0; jj < 16; ++jj) { z[jj] = __expf(z[jj] - m); s += z[jj]; }
    s += __shfl_xor(s, 32, 64);
    float inv = 1.f / s;
    bf16x8 o0, o1;
#pragma unroll
    for (int jj = 0; jj < 8; ++jj) o0[jj] = (bf16)(z[jj] * inv);
#pragma unroll
    for (int jj = 0; jj < 8; ++jj) o1[jj] = (bf16)(z[8 + jj] * inv);
    bf16x8* dst = (bf16x8*)(attn + ((((size_t)bi * 32 + l) * 32 + r1) * 32 + half * 16));
    dst[0] = o0;
    dst[1] = o1;
}

// ---------------------------------------------------------------- K3: fused Yh+Yw -> T (bf16, row-major) — r0 proven version
__global__ __launch_bounds__(256) void k_mix(const bf16* __restrict__ x,
                                             const bf16* __restrict__ attn_h,
                                             const bf16* __restrict__ attn_w,
                                             bf16* __restrict__ T) {
    __shared__ bf16 Xs[1024 * 16];      // [pixel][16 cols]  32 KB
    __shared__ bf16 Ts[1024 * 16];      // Yh park           32 KB
    int n = blockIdx.x;                 // 0..1535
    int a = n >> 5, r = n & 31;
    int q = a * 8 + (r & 7);            // 0..383
    int bi = q / 6, cq = q % 6;
    int c = cq * 4 + (r >> 3);          // 0..23
    int dbase = c * 16;
    int tid = threadIdx.x;
    int wv = tid >> 6, lane = tid & 63;
    int n16 = lane & 15, quad = lane >> 4;

    // ---- stage x[bi][:, dbase:dbase+16] -> Xs (lane-linear 16B chunks)
    const char* gbase = (const char*)(x + (size_t)bi * 1024 * 384 + dbase);
#pragma unroll
    for (int it = 0; it < 8; ++it) {
        int p0 = wv * 256 + it * 32;                 // 32 pixels per inst
        const char* g = gbase + (size_t)(p0 + (lane >> 1)) * 768 + (lane & 1) * 16;
        char* l = (char*)Xs + p0 * 32 + lane * 16;
        async_copy16(l, g);
    }
    __syncthreads();

    // ---- phase 1: Yh[h,w,d] = sum_j ah[w,h,j] x[j,w,d] -> Ts
#pragma unroll
    for (int wl = 0; wl < 8; ++wl) {
        int w = wv * 8 + wl;
        const bf16* ab = attn_h + ((size_t)(bi * 32 + w) * 32) * 32;
        bf16x8 af0 = *(const bf16x8*)(ab + n16 * 32 + quad * 8);
        bf16x8 af1 = *(const bf16x8*)(ab + (16 + n16) * 32 + quad * 8);
        bf16x8 bfrag;
#pragma unroll
        for (int i = 0; i < 8; ++i) {
            int j = quad * 8 + i;
            bfrag[i] = Xs[(j * 32 + w) * 16 + n16];
        }
        floatx4 c0 = {0.f, 0.f, 0.f, 0.f}, c1 = {0.f, 0.f, 0.f, 0.f};
        c0 = __builtin_amdgcn_mfma_f32_16x16x32_bf16(af0, bfrag, c0, 0, 0, 0);
        c1 = __builtin_amdgcn_mfma_f32_16x16x32_bf16(af1, bfrag, c1, 0, 0, 0);
#pragma unroll
        for (int rr = 0; rr < 4; ++rr) {
            int h0 = quad * 4 + rr;
            Ts[(h0 * 32 + w) * 16 + n16]        = (bf16)c0[rr];
            Ts[((16 + h0) * 32 + w) * 16 + n16] = (bf16)c1[rr];
        }
    }
    __syncthreads();

    // ---- phase 2: Yw[h,w,d] = sum_j aw[h,w,j] x[h,j,d]; T = Yh + Yw
#pragma unroll
    for (int hl = 0; hl < 8; ++hl) {
        int h = wv * 8 + hl;
        const bf16* ab = attn_w + ((size_t)(bi * 32 + h) * 32) * 32;
        bf16x8 af0 = *(const bf16x8*)(ab + n16 * 32 + quad * 8);
        bf16x8 af1 = *(const bf16x8*)(ab + (16 + n16) * 32 + quad * 8);
        bf16x8 bfrag;
#pragma unroll
        for (int i = 0; i < 8; ++i) {
            int j = quad * 8 + i;
            bfrag[i] = Xs[(h * 32 + j) * 16 + n16];
        }
        floatx4 c0 = {0.f, 0.f, 0.f, 0.f}, c1 = {0.f, 0.f, 0.f, 0.f};
        c0 = __builtin_amdgcn_mfma_f32_16x16x32_bf16(af0, bfrag, c0, 0, 0, 0);
        c1 = __builtin_amdgcn_mfma_f32_16x16x32_bf16(af1, bfrag, c1, 0, 0, 0);
        bf16* Tr = T + ((size_t)(bi * 32 + h) * 32) * 384 + dbase;
#pragma unroll
        for (int rr = 0; rr < 4; ++rr) {
            int w0 = quad * 4 + rr;
            Tr[(size_t)w0 * 384 + n16] =
                (bf16)(c0[rr] + (float)Ts[(h * 32 + w0) * 16 + n16]);
            Tr[(size_t)(16 + w0) * 384 + n16] =
                (bf16)(c1[rr] + (float)Ts[(h * 32 + 16 + w0) * 16 + n16]);
        }
    }
}

// ---------------------------------------------------------------- K5: out = [T|xb] @ Wfull^T + bco   (M=65536,N=384,K=768), out fp32
// r4 proven winner (63.5-64.4 us): reg-staged, LDP=72 padded LDS,
// 2 barriers/K-step, T14 issue-early/write-late ping-pong. DO NOT TOUCH.
#define LDP 72
__global__ __launch_bounds__(256) void k_gemm(const bf16* __restrict__ T, const bf16* __restrict__ x,
                                              const bf16* __restrict__ Wfull, const float* __restrict__ bco,
                                              float* __restrict__ out) {
    __shared__ bf16 As[128 * LDP];
    __shared__ bf16 Bs[128 * LDP];
    int bx = blockIdx.x;               // 0..1535
    int gid = (bx & 7) * 192 + (bx >> 3);
    int nt = gid % 3, pt = gid / 3;
    int obase = nt * 128;
    int pbase = pt * 128;
    int tid = threadIdx.x;
    int wv = tid >> 6, lane = tid & 63;
    int wm = wv & 1, wn = wv >> 1;
    int n16 = lane & 15, quad = lane >> 4;
    int lrow = tid >> 3;           // 0..31
    int lchunk = tid & 7;          // 0..7
    floatx4 zero = {0.f, 0.f, 0.f, 0.f};
    floatx4 acc[4][4];
#pragma unroll
    for (int i = 0; i < 4; ++i)
#pragma unroll
        for (int j = 0; j < 4; ++j) acc[i][j] = zero;

    const bf16* Bg0 = Wfull + (size_t)obase * 768;

    auto load_tile = [&](int kt, bf16x8 (&av)[4], bf16x8 (&bv)[4]) {
        const bf16* Asrc = (kt < 6) ? (T + (size_t)pbase * 384 + kt * 64)
                                    : (x + (size_t)pbase * 384 + (kt - 6) * 64);
        const bf16* Bsrc = Bg0 + kt * 64;
#pragma unroll
        for (int s = 0; s < 4; ++s)
            av[s] = *(const bf16x8*)(Asrc + (size_t)(s * 32 + lrow) * 384 + lchunk * 8);
#pragma unroll
        for (int s = 0; s < 4; ++s)
            bv[s] = *(const bf16x8*)(Bsrc + (size_t)(s * 32 + lrow) * 768 + lchunk * 8);
    };

    auto step = [&](int kt, bf16x8 (&av)[4], bf16x8 (&bv)[4],
                    bf16x8 (&nav)[4], bf16x8 (&nbv)[4]) {
        __syncthreads();           // previous iteration's LDS reads done
#pragma unroll
        for (int s = 0; s < 4; ++s)
            *(bf16x8*)(As + (s * 32 + lrow) * LDP + lchunk * 8) = av[s];
#pragma unroll
        for (int s = 0; s < 4; ++s)
            *(bf16x8*)(Bs + (s * 32 + lrow) * LDP + lchunk * 8) = bv[s];
        __syncthreads();
        if (kt < 11) load_tile(kt + 1, nav, nbv);   // issue; consumed next step
#pragma unroll
        for (int ks = 0; ks < 2; ++ks) {
            bf16x8 a[4], b[4];
#pragma unroll
            for (int i = 0; i < 4; ++i)
                a[i] = *(const bf16x8*)(As + (wm * 64 + i * 16 + n16) * LDP + ks * 32 + quad * 8);
#pragma unroll
            for (int i = 0; i < 4; ++i)
                b[i] = *(const bf16x8*)(Bs + (wn * 64 + i * 16 + n16) * LDP + ks * 32 + quad * 8);
#pragma unroll
            for (int i = 0; i < 4; ++i)
#pragma unroll
                for (int j = 0; j < 4; ++j)
                    acc[i][j] = __builtin_amdgcn_mfma_f32_16x16x32_bf16(a[i], b[j], acc[i][j], 0, 0, 0);
        }
    };

    bf16x8 avA[4], bvA[4], avB[4], bvB[4];
    load_tile(0, avA, bvA);
    for (int kt = 0; kt < 12; kt += 2) {
        step(kt,     avA, bvA, avB, bvB);
        step(kt + 1, avB, bvB, avA, bvA);
    }

    // epilogue: fp32 output
#pragma unroll
    for (int j = 0; j < 4; ++j) {
        int o = obase + wn * 64 + j * 16 + n16;
        float bcv = bco[o];
#pragma unroll
        for (int i = 0; i < 4; ++i) {
            int prow = pbase + wm * 64 + i * 16 + quad * 4;
#pragma unroll
            for (int r = 0; r < 4; ++r)
                out[(size_t)(prow + r) * 384 + o] = acc[i][j][r] + bcv;
        }
    }
}

// ---------------------------------------------------------------- launch
extern "C" void kernel_launch(void* const* d_in, const int* in_sizes, int n_in,
                              void* d_out, int out_size, void* d_ws, size_t ws_size,
                              hipStream_t stream) {
    const float* x   = (const float*)d_in[0];
    const float* Wc  = (const float*)d_in[1];
    const float* bc  = (const float*)d_in[2];
    const float* Wo  = (const float*)d_in[3];
    const float* bo  = (const float*)d_in[4];
    const float* W1h = (const float*)d_in[5];
    const float* b1h = (const float*)d_in[6];
    const float* W2h = (const float*)d_in[7];
    const float* b2h = (const float*)d_in[8];
    const float* W1w = (const float*)d_in[9];
    const float* b1w = (const float*)d_in[10];
    const float* W2w = (const float*)d_in[11];
    const float* b2w = (const float*)d_in[12];
    float* out = (float*)d_out;

    char* ws = (char*)d_ws;
    size_t off = 0;
    auto alloc = [&](size_t bytes) {
        void* p = ws + off;
        off = (off + bytes + 255) & ~(size_t)255;
        return p;
    };
    bf16*  xb     = (bf16*)alloc((size_t)NPIX * 384 * 2);  // bf16 copy of x, row-major
    float* yh     = (float*)alloc((size_t)131072 * 4);     // [B][2][32][32]
    float* yw     = (float*)alloc((size_t)131072 * 4);
    bf16*  attn_h = (bf16*)alloc((size_t)2097152 * 2);     // [B][W][H][H]
    bf16*  attn_w = (bf16*)alloc((size_t)2097152 * 2);     // [B][H][W][W]
    bf16*  T      = (bf16*)alloc((size_t)NPIX * 384 * 2);  // Yh+Yw, row-major
    bf16*  Wfull  = (bf16*)alloc((size_t)384 * 768 * 2);   // [Wo | Wo@Wc]
    float* bco    = (float*)alloc((size_t)384 * 4);

    hipLaunchKernelGGL(k_prep_w, dim3(385), dim3(384), 0, stream, Wc, bc, Wo, bo, Wfull, bco);
    hipLaunchKernelGGL(k_proj, dim3(512), dim3(256), 0, stream, x, xb, W1h, b1h, W1w, b1w, yh, yw);
    hipLaunchKernelGGL(k_attn, dim3(1024), dim3(256), 0, stream, yh, yw, W2h, b2h, W2w, b2w, attn_h, attn_w);
    hipLaunchKernelGGL(k_mix, dim3(1536), dim3(256), 0, stream, xb, attn_h, attn_w, T);
    hipLaunchKernelGGL(k_gemm, dim3(1536), dim3(256), 0, stream, T, xb, Wfull, bco, out);
}

// Round 9
// 317.671 us; speedup vs baseline: 1.0767x; 1.0398x over previous
//
#include <hip/hip_runtime.h>
#include <hip/hip_bf16.h>
#include <cstdint>
#include <cstddef>

typedef __bf16 bf16;
typedef __attribute__((ext_vector_type(8))) __bf16 bf16x8;
typedef __attribute__((ext_vector_type(4))) float floatx4;

#define NPIX 65536   // B*H*W

__device__ inline void async_copy16(void* lds, const void* g) {
    __builtin_amdgcn_global_load_lds(
        (const __attribute__((address_space(1))) void*)g,
        (__attribute__((address_space(3))) void*)lds, 16, 0, 0);
}

// ---------------------------------------------------------------- K0: Wfull = [Wo | Wo@Wc] (bf16), bco = Wo@bc + bo (fp32)
__global__ void k_prep_w(const float* __restrict__ Wc, const float* __restrict__ bc,
                         const float* __restrict__ Wo, const float* __restrict__ bo,
                         bf16* __restrict__ Wfull, float* __restrict__ bco) {
    int blk = blockIdx.x;
    int t = threadIdx.x;          // 0..383
    if (blk < 384) {
        int o = blk;
        float acc = 0.f;
        for (int d = 0; d < 384; ++d)
            acc += Wo[o * 384 + d] * Wc[d * 384 + t];
        Wfull[(size_t)o * 768 + t]       = (bf16)Wo[o * 384 + t];
        Wfull[(size_t)o * 768 + 384 + t] = (bf16)acc;
    } else {
        int o = t;
        float acc = bo[o];
        for (int d = 0; d < 384; ++d)
            acc += Wo[o * 384 + d] * bc[d];
        bco[o] = acc;
    }
}

// ---------------------------------------------------------------- K1: convert + projections (E=2), xb row-major [pixel][384]
// r0 low-VGPR 8-lane-per-pixel structure, but W1h/W1w staged in LDS (6 KB)
// once per block: per-lane VMEM drops 66 -> ~18; W reads become LDS
// broadcasts (2-way lane aliasing = free).
__global__ __launch_bounds__(256) void k_proj(const float* __restrict__ xf, bf16* __restrict__ xb,
                       const float* __restrict__ W1h, const float* __restrict__ b1h,
                       const float* __restrict__ W1w, const float* __restrict__ b1w,
                       float* __restrict__ yh, float* __restrict__ yw) {
    __shared__ float Wh[768], Ww[768];   // [e=2][384] each
    int t  = threadIdx.x;
    if (t < 192) {
        ((float4*)Wh)[t] = ((const float4*)W1h)[t];
        ((float4*)Ww)[t] = ((const float4*)W1w)[t];
    }
    __syncthreads();
    int lg = t & 7;                 // lane within 8-lane pixel group
    int pg = t >> 3;                // pixel group in block (0..31)
    int p  = blockIdx.x * 32 + pg;  // pixel id
    int b = p >> 10, h = (p >> 5) & 31, w = p & 31;
    const float4* xp4 = (const float4*)(xf + (size_t)p * 384);
    float a0 = 0.f, a1 = 0.f, a2 = 0.f, a3 = 0.f;
#pragma unroll
    for (int j = 0; j < 6; ++j) {
        int c = j * 8 + lg;         // 8-element chunk 0..47
        float4 xa = xp4[c * 2], xcv = xp4[c * 2 + 1];
        bf16x8 v;
        v[0] = (bf16)xa.x; v[1] = (bf16)xa.y; v[2] = (bf16)xa.z; v[3] = (bf16)xa.w;
        v[4] = (bf16)xcv.x; v[5] = (bf16)xcv.y; v[6] = (bf16)xcv.z; v[7] = (bf16)xcv.w;
        *(bf16x8*)(xb + (size_t)p * 384 + c * 8) = v;
        float4 h0a = *(const float4*)(Wh + c * 8);
        float4 h0b = *(const float4*)(Wh + c * 8 + 4);
        float4 h1a = *(const float4*)(Wh + 384 + c * 8);
        float4 h1b = *(const float4*)(Wh + 384 + c * 8 + 4);
        float4 w0a = *(const float4*)(Ww + c * 8);
        float4 w0b = *(const float4*)(Ww + c * 8 + 4);
        float4 w1a = *(const float4*)(Ww + 384 + c * 8);
        float4 w1b = *(const float4*)(Ww + 384 + c * 8 + 4);
        a0 += xa.x*h0a.x + xa.y*h0a.y + xa.z*h0a.z + xa.w*h0a.w
            + xcv.x*h0b.x + xcv.y*h0b.y + xcv.z*h0b.z + xcv.w*h0b.w;
        a1 += xa.x*h1a.x + xa.y*h1a.y + xa.z*h1a.z + xa.w*h1a.w
            + xcv.x*h1b.x + xcv.y*h1b.y + xcv.z*h1b.z + xcv.w*h1b.w;
        a2 += xa.x*w0a.x + xa.y*w0a.y + xa.z*w0a.z + xa.w*w0a.w
            + xcv.x*w0b.x + xcv.y*w0b.y + xcv.z*w0b.z + xcv.w*w0b.w;
        a3 += xa.x*w1a.x + xa.y*w1a.y + xa.z*w1a.z + xa.w*w1a.w
            + xcv.x*w1b.x + xcv.y*w1b.y + xcv.z*w1b.z + xcv.w*w1b.w;
    }
#pragma unroll
    for (int m = 1; m < 8; m <<= 1) {
        a0 += __shfl_xor(a0, m, 64);
        a1 += __shfl_xor(a1, m, 64);
        a2 += __shfl_xor(a2, m, 64);
        a3 += __shfl_xor(a3, m, 64);
    }
    if (lg == 0) {
        yh[((b * 2 + 0) * 32 + h) * 32 + w] = a0 + b1h[0];
        yh[((b * 2 + 1) * 32 + h) * 32 + w] = a1 + b1h[1];
        yw[((b * 2 + 0) * 32 + w) * 32 + h] = a2 + b1w[0];
        yw[((b * 2 + 1) * 32 + w) * 32 + h] = a3 + b1w[1];
    }
}

// ---------------------------------------------------------------- K2: grouped mix + softmax -> attn[b][l][r1][r2] (bf16)
// 256-thread blocks, 4 waves each handling one (variant, bi, r1) unit.
__global__ __launch_bounds__(256) void k_attn(const float* __restrict__ yh_in, const float* __restrict__ yw_in,
                       const float* __restrict__ W2h, const float* __restrict__ b2h,
                       const float* __restrict__ W2w, const float* __restrict__ b2w,
                       bf16* __restrict__ attn_h, bf16* __restrict__ attn_w) {
    int blk = blockIdx.x * 4 + (threadIdx.x >> 6);   // 0..4095
    const float* yproj; const float* W2; const float* b2; bf16* attn;
    if (blk < 2048) { yproj = yh_in; W2 = W2h; b2 = b2h; attn = attn_h; }
    else            { yproj = yw_in; W2 = W2w; b2 = b2w; attn = attn_w; blk -= 2048; }
    int bi = blk >> 5, r1 = blk & 31;
    int g = r1 >> 2;
    int cb = g * 8;
    int e = cb >> 5, rb = cb & 31;        // 8 consecutive rows of plane e
    int lane = threadIdx.x & 63;
    int l = lane & 31, half = lane >> 5;
    float yv[8];
    const float* ybase = yproj + (((bi * 2 + e) * 32 + rb) * 32 + l);
#pragma unroll
    for (int c = 0; c < 8; ++c) yv[c] = ybase[c * 32];
    float z[16];
#pragma unroll
    for (int jj = 0; jj < 16; ++jj) {
        int r2 = half * 16 + jj;
        int row = r1 * 32 + r2;
        const float4* wp = (const float4*)(W2 + (size_t)row * 8);
        float4 wa = wp[0], wb = wp[1];
        z[jj] = b2[row]
              + yv[0]*wa.x + yv[1]*wa.y + yv[2]*wa.z + yv[3]*wa.w
              + yv[4]*wb.x + yv[5]*wb.y + yv[6]*wb.z + yv[7]*wb.w;
    }
    float m = -1e30f;
#pragma unroll
    for (int jj = 0; jj < 16; ++jj) m = fmaxf(m, z[jj]);
    m = fmaxf(m, __shfl_xor(m, 32, 64));
    float s = 0.f;
#pragma unroll
    for (int jj = 0; jj < 16; ++jj) { z[jj] = __expf(z[jj] - m); s += z[jj]; }
    s += __shfl_xor(s, 32, 64);
    float inv = 1.f / s;
    bf16x8 o0, o1;
#pragma unroll
    for (int jj = 0; jj < 8; ++jj) o0[jj] = (bf16)(z[jj] * inv);
#pragma unroll
    for (int jj = 0; jj < 8; ++jj) o1[jj] = (bf16)(z[8 + jj] * inv);
    bf16x8* dst = (bf16x8*)(attn + ((((size_t)bi * 32 + l) * 32 + r1) * 32 + half * 16));
    dst[0] = o0;
    dst[1] = o1;
}

// ---------------------------------------------------------------- K3: fused Yh+Yw -> T (bf16, row-major) — r0 proven version
__global__ __launch_bounds__(256) void k_mix(const bf16* __restrict__ x,
                                             const bf16* __restrict__ attn_h,
                                             const bf16* __restrict__ attn_w,
                                             bf16* __restrict__ T) {
    __shared__ bf16 Xs[1024 * 16];      // [pixel][16 cols]  32 KB
    __shared__ bf16 Ts[1024 * 16];      // Yh park           32 KB
    int n = blockIdx.x;                 // 0..1535
    int a = n >> 5, r = n & 31;
    int q = a * 8 + (r & 7);            // 0..383
    int bi = q / 6, cq = q % 6;
    int c = cq * 4 + (r >> 3);          // 0..23
    int dbase = c * 16;
    int tid = threadIdx.x;
    int wv = tid >> 6, lane = tid & 63;
    int n16 = lane & 15, quad = lane >> 4;

    // ---- stage x[bi][:, dbase:dbase+16] -> Xs (lane-linear 16B chunks)
    const char* gbase = (const char*)(x + (size_t)bi * 1024 * 384 + dbase);
#pragma unroll
    for (int it = 0; it < 8; ++it) {
        int p0 = wv * 256 + it * 32;                 // 32 pixels per inst
        const char* g = gbase + (size_t)(p0 + (lane >> 1)) * 768 + (lane & 1) * 16;
        char* l = (char*)Xs + p0 * 32 + lane * 16;
        async_copy16(l, g);
    }
    __syncthreads();

    // ---- phase 1: Yh[h,w,d] = sum_j ah[w,h,j] x[j,w,d] -> Ts
#pragma unroll
    for (int wl = 0; wl < 8; ++wl) {
        int w = wv * 8 + wl;
        const bf16* ab = attn_h + ((size_t)(bi * 32 + w) * 32) * 32;
        bf16x8 af0 = *(const bf16x8*)(ab + n16 * 32 + quad * 8);
        bf16x8 af1 = *(const bf16x8*)(ab + (16 + n16) * 32 + quad * 8);
        bf16x8 bfrag;
#pragma unroll
        for (int i = 0; i < 8; ++i) {
            int j = quad * 8 + i;
            bfrag[i] = Xs[(j * 32 + w) * 16 + n16];
        }
        floatx4 c0 = {0.f, 0.f, 0.f, 0.f}, c1 = {0.f, 0.f, 0.f, 0.f};
        c0 = __builtin_amdgcn_mfma_f32_16x16x32_bf16(af0, bfrag, c0, 0, 0, 0);
        c1 = __builtin_amdgcn_mfma_f32_16x16x32_bf16(af1, bfrag, c1, 0, 0, 0);
#pragma unroll
        for (int rr = 0; rr < 4; ++rr) {
            int h0 = quad * 4 + rr;
            Ts[(h0 * 32 + w) * 16 + n16]        = (bf16)c0[rr];
            Ts[((16 + h0) * 32 + w) * 16 + n16] = (bf16)c1[rr];
        }
    }
    __syncthreads();

    // ---- phase 2: Yw[h,w,d] = sum_j aw[h,w,j] x[h,j,d]; T = Yh + Yw
#pragma unroll
    for (int hl = 0; hl < 8; ++hl) {
        int h = wv * 8 + hl;
        const bf16* ab = attn_w + ((size_t)(bi * 32 + h) * 32) * 32;
        bf16x8 af0 = *(const bf16x8*)(ab + n16 * 32 + quad * 8);
        bf16x8 af1 = *(const bf16x8*)(ab + (16 + n16) * 32 + quad * 8);
        bf16x8 bfrag;
#pragma unroll
        for (int i = 0; i < 8; ++i) {
            int j = quad * 8 + i;
            bfrag[i] = Xs[(h * 32 + j) * 16 + n16];
        }
        floatx4 c0 = {0.f, 0.f, 0.f, 0.f}, c1 = {0.f, 0.f, 0.f, 0.f};
        c0 = __builtin_amdgcn_mfma_f32_16x16x32_bf16(af0, bfrag, c0, 0, 0, 0);
        c1 = __builtin_amdgcn_mfma_f32_16x16x32_bf16(af1, bfrag, c1, 0, 0, 0);
        bf16* Tr = T + ((size_t)(bi * 32 + h) * 32) * 384 + dbase;
#pragma unroll
        for (int rr = 0; rr < 4; ++rr) {
            int w0 = quad * 4 + rr;
            Tr[(size_t)w0 * 384 + n16] =
                (bf16)(c0[rr] + (float)Ts[(h * 32 + w0) * 16 + n16]);
            Tr[(size_t)(16 + w0) * 384 + n16] =
                (bf16)(c1[rr] + (float)Ts[(h * 32 + 16 + w0) * 16 + n16]);
        }
    }
}

// ---------------------------------------------------------------- K5: out = [T|xb] @ Wfull^T + bco   (M=65536,N=384,K=768), out fp32
// r4 proven winner (63.5-64.4 us): reg-staged, LDP=72 padded LDS,
// 2 barriers/K-step, T14 issue-early/write-late ping-pong. DO NOT TOUCH.
#define LDP 72
__global__ __launch_bounds__(256) void k_gemm(const bf16* __restrict__ T, const bf16* __restrict__ x,
                                              const bf16* __restrict__ Wfull, const float* __restrict__ bco,
                                              float* __restrict__ out) {
    __shared__ bf16 As[128 * LDP];
    __shared__ bf16 Bs[128 * LDP];
    int bx = blockIdx.x;               // 0..1535
    int gid = (bx & 7) * 192 + (bx >> 3);
    int nt = gid % 3, pt = gid / 3;
    int obase = nt * 128;
    int pbase = pt * 128;
    int tid = threadIdx.x;
    int wv = tid >> 6, lane = tid & 63;
    int wm = wv & 1, wn = wv >> 1;
    int n16 = lane & 15, quad = lane >> 4;
    int lrow = tid >> 3;           // 0..31
    int lchunk = tid & 7;          // 0..7
    floatx4 zero = {0.f, 0.f, 0.f, 0.f};
    floatx4 acc[4][4];
#pragma unroll
    for (int i = 0; i < 4; ++i)
#pragma unroll
        for (int j = 0; j < 4; ++j) acc[i][j] = zero;

    const bf16* Bg0 = Wfull + (size_t)obase * 768;

    auto load_tile = [&](int kt, bf16x8 (&av)[4], bf16x8 (&bv)[4]) {
        const bf16* Asrc = (kt < 6) ? (T + (size_t)pbase * 384 + kt * 64)
                                    : (x + (size_t)pbase * 384 + (kt - 6) * 64);
        const bf16* Bsrc = Bg0 + kt * 64;
#pragma unroll
        for (int s = 0; s < 4; ++s)
            av[s] = *(const bf16x8*)(Asrc + (size_t)(s * 32 + lrow) * 384 + lchunk * 8);
#pragma unroll
        for (int s = 0; s < 4; ++s)
            bv[s] = *(const bf16x8*)(Bsrc + (size_t)(s * 32 + lrow) * 768 + lchunk * 8);
    };

    auto step = [&](int kt, bf16x8 (&av)[4], bf16x8 (&bv)[4],
                    bf16x8 (&nav)[4], bf16x8 (&nbv)[4]) {
        __syncthreads();           // previous iteration's LDS reads done
#pragma unroll
        for (int s = 0; s < 4; ++s)
            *(bf16x8*)(As + (s * 32 + lrow) * LDP + lchunk * 8) = av[s];
#pragma unroll
        for (int s = 0; s < 4; ++s)
            *(bf16x8*)(Bs + (s * 32 + lrow) * LDP + lchunk * 8) = bv[s];
        __syncthreads();
        if (kt < 11) load_tile(kt + 1, nav, nbv);   // issue; consumed next step
#pragma unroll
        for (int ks = 0; ks < 2; ++ks) {
            bf16x8 a[4], b[4];
#pragma unroll
            for (int i = 0; i < 4; ++i)
                a[i] = *(const bf16x8*)(As + (wm * 64 + i * 16 + n16) * LDP + ks * 32 + quad * 8);
#pragma unroll
            for (int i = 0; i < 4; ++i)
                b[i] = *(const bf16x8*)(Bs + (wn * 64 + i * 16 + n16) * LDP + ks * 32 + quad * 8);
#pragma unroll
            for (int i = 0; i < 4; ++i)
#pragma unroll
                for (int j = 0; j < 4; ++j)
                    acc[i][j] = __builtin_amdgcn_mfma_f32_16x16x32_bf16(a[i], b[j], acc[i][j], 0, 0, 0);
        }
    };

    bf16x8 avA[4], bvA[4], avB[4], bvB[4];
    load_tile(0, avA, bvA);
    for (int kt = 0; kt < 12; kt += 2) {
        step(kt,     avA, bvA, avB, bvB);
        step(kt + 1, avB, bvB, avA, bvA);
    }

    // epilogue: fp32 output
#pragma unroll
    for (int j = 0; j < 4; ++j) {
        int o = obase + wn * 64 + j * 16 + n16;
        float bcv = bco[o];
#pragma unroll
        for (int i = 0; i < 4; ++i) {
            int prow = pbase + wm * 64 + i * 16 + quad * 4;
#pragma unroll
            for (int r = 0; r < 4; ++r)
                out[(size_t)(prow + r) * 384 + o] = acc[i][j][r] + bcv;
        }
    }
}

// ---------------------------------------------------------------- launch
extern "C" void kernel_launch(void* const* d_in, const int* in_sizes, int n_in,
                              void* d_out, int out_size, void* d_ws, size_t ws_size,
                              hipStream_t stream) {
    const float* x   = (const float*)d_in[0];
    const float* Wc  = (const float*)d_in[1];
    const float* bc  = (const float*)d_in[2];
    const float* Wo  = (const float*)d_in[3];
    const float* bo  = (const float*)d_in[4];
    const float* W1h = (const float*)d_in[5];
    const float* b1h = (const float*)d_in[6];
    const float* W2h = (const float*)d_in[7];
    const float* b2h = (const float*)d_in[8];
    const float* W1w = (const float*)d_in[9];
    const float* b1w = (const float*)d_in[10];
    const float* W2w = (const float*)d_in[11];
    const float* b2w = (const float*)d_in[12];
    float* out = (float*)d_out;

    char* ws = (char*)d_ws;
    size_t off = 0;
    auto alloc = [&](size_t bytes) {
        void* p = ws + off;
        off = (off + bytes + 255) & ~(size_t)255;
        return p;
    };
    bf16*  xb     = (bf16*)alloc((size_t)NPIX * 384 * 2);  // bf16 copy of x, row-major
    float* yh     = (float*)alloc((size_t)131072 * 4);     // [B][2][32][32]
    float* yw     = (float*)alloc((size_t)131072 * 4);
    bf16*  attn_h = (bf16*)alloc((size_t)2097152 * 2);     // [B][W][H][H]
    bf16*  attn_w = (bf16*)alloc((size_t)2097152 * 2);     // [B][H][W][W]
    bf16*  T      = (bf16*)alloc((size_t)NPIX * 384 * 2);  // Yh+Yw, row-major
    bf16*  Wfull  = (bf16*)alloc((size_t)384 * 768 * 2);   // [Wo | Wo@Wc]
    float* bco    = (float*)alloc((size_t)384 * 4);

    hipLaunchKernelGGL(k_prep_w, dim3(385), dim3(384), 0, stream, Wc, bc, Wo, bo, Wfull, bco);
    hipLaunchKernelGGL(k_proj, dim3(2048), dim3(256), 0, stream, x, xb, W1h, b1h, W1w, b1w, yh, yw);
    hipLaunchKernelGGL(k_attn, dim3(1024), dim3(256), 0, stream, yh, yw, W2h, b2h, W2w, b2w, attn_h, attn_w);
    hipLaunchKernelGGL(k_mix, dim3(1536), dim3(256), 0, stream, xb, attn_h, attn_w, T);
    hipLaunchKernelGGL(k_gemm, dim3(1536), dim3(256), 0, stream, T, xb, Wfull, bco, out);
}

// Round 10
// 313.123 us; speedup vs baseline: 1.0924x; 1.0145x over previous
//
#include <hip/hip_runtime.h>
#include <hip/hip_bf16.h>
#include <cstdint>
#include <cstddef>

typedef __bf16 bf16;
typedef __attribute__((ext_vector_type(8))) __bf16 bf16x8;
typedef __attribute__((ext_vector_type(4))) float floatx4;

#define NPIX 65536   // B*H*W

__device__ inline void async_copy16(void* lds, const void* g) {
    __builtin_amdgcn_global_load_lds(
        (const __attribute__((address_space(1))) void*)g,
        (__attribute__((address_space(3))) void*)lds, 16, 0, 0);
}

// ---------------------------------------------------------------- K1: convert + projections (E=2), xb row-major [pixel][384]
// MERGED with k_prep_w: blocks >= 2048 compute Wfull/bco (independent work,
// overlaps proj instead of a serialized extra dispatch).
__global__ __launch_bounds__(256) void k_proj(const float* __restrict__ xf, bf16* __restrict__ xb,
                       const float* __restrict__ W1h, const float* __restrict__ b1h,
                       const float* __restrict__ W1w, const float* __restrict__ b1w,
                       float* __restrict__ yh, float* __restrict__ yw,
                       const float* __restrict__ Wc, const float* __restrict__ bc,
                       const float* __restrict__ Wo, const float* __restrict__ bo,
                       bf16* __restrict__ Wfull, float* __restrict__ bco) {
    if (blockIdx.x >= 2048) {
        // ---- prep_w part: 769 blocks. pb<768: (o, half of cols); pb==768: bco.
        int pb = blockIdx.x - 2048;
        int tid = threadIdx.x;
        if (pb < 768) {
            int o = pb >> 1;
            int t = (pb & 1) * 256 + tid;     // column
            if (t < 384) {
                float acc = 0.f;
                for (int d = 0; d < 384; ++d)
                    acc += Wo[o * 384 + d] * Wc[d * 384 + t];
                Wfull[(size_t)o * 768 + t]       = (bf16)Wo[o * 384 + t];
                Wfull[(size_t)o * 768 + 384 + t] = (bf16)acc;
            }
        } else {
            for (int o = tid; o < 384; o += 256) {
                float acc = bo[o];
                for (int d = 0; d < 384; ++d)
                    acc += Wo[o * 384 + d] * bc[d];
                bco[o] = acc;
            }
        }
        return;
    }
    // ---- proj part (r9 proven: LDS-staged W, 8-lane-per-pixel)
    __shared__ float Wh[768], Ww[768];   // [e=2][384] each
    int t  = threadIdx.x;
    if (t < 192) {
        ((float4*)Wh)[t] = ((const float4*)W1h)[t];
        ((float4*)Ww)[t] = ((const float4*)W1w)[t];
    }
    __syncthreads();
    int lg = t & 7;                 // lane within 8-lane pixel group
    int pg = t >> 3;                // pixel group in block (0..31)
    int p  = blockIdx.x * 32 + pg;  // pixel id
    int b = p >> 10, h = (p >> 5) & 31, w = p & 31;
    const float4* xp4 = (const float4*)(xf + (size_t)p * 384);
    float a0 = 0.f, a1 = 0.f, a2 = 0.f, a3 = 0.f;
#pragma unroll
    for (int j = 0; j < 6; ++j) {
        int c = j * 8 + lg;         // 8-element chunk 0..47
        float4 xa = xp4[c * 2], xcv = xp4[c * 2 + 1];
        bf16x8 v;
        v[0] = (bf16)xa.x; v[1] = (bf16)xa.y; v[2] = (bf16)xa.z; v[3] = (bf16)xa.w;
        v[4] = (bf16)xcv.x; v[5] = (bf16)xcv.y; v[6] = (bf16)xcv.z; v[7] = (bf16)xcv.w;
        *(bf16x8*)(xb + (size_t)p * 384 + c * 8) = v;
        float4 h0a = *(const float4*)(Wh + c * 8);
        float4 h0b = *(const float4*)(Wh + c * 8 + 4);
        float4 h1a = *(const float4*)(Wh + 384 + c * 8);
        float4 h1b = *(const float4*)(Wh + 384 + c * 8 + 4);
        float4 w0a = *(const float4*)(Ww + c * 8);
        float4 w0b = *(const float4*)(Ww + c * 8 + 4);
        float4 w1a = *(const float4*)(Ww + 384 + c * 8);
        float4 w1b = *(const float4*)(Ww + 384 + c * 8 + 4);
        a0 += xa.x*h0a.x + xa.y*h0a.y + xa.z*h0a.z + xa.w*h0a.w
            + xcv.x*h0b.x + xcv.y*h0b.y + xcv.z*h0b.z + xcv.w*h0b.w;
        a1 += xa.x*h1a.x + xa.y*h1a.y + xa.z*h1a.z + xa.w*h1a.w
            + xcv.x*h1b.x + xcv.y*h1b.y + xcv.z*h1b.z + xcv.w*h1b.w;
        a2 += xa.x*w0a.x + xa.y*w0a.y + xa.z*w0a.z + xa.w*w0a.w
            + xcv.x*w0b.x + xcv.y*w0b.y + xcv.z*w0b.z + xcv.w*w0b.w;
        a3 += xa.x*w1a.x + xa.y*w1a.y + xa.z*w1a.z + xa.w*w1a.w
            + xcv.x*w1b.x + xcv.y*w1b.y + xcv.z*w1b.z + xcv.w*w1b.w;
    }
#pragma unroll
    for (int m = 1; m < 8; m <<= 1) {
        a0 += __shfl_xor(a0, m, 64);
        a1 += __shfl_xor(a1, m, 64);
        a2 += __shfl_xor(a2, m, 64);
        a3 += __shfl_xor(a3, m, 64);
    }
    if (lg == 0) {
        yh[((b * 2 + 0) * 32 + h) * 32 + w] = a0 + b1h[0];
        yh[((b * 2 + 1) * 32 + h) * 32 + w] = a1 + b1h[1];
        yw[((b * 2 + 0) * 32 + w) * 32 + h] = a2 + b1w[0];
        yw[((b * 2 + 1) * 32 + w) * 32 + h] = a3 + b1w[1];
    }
}

// ---------------------------------------------------------------- K2: grouped mix + softmax -> attn[b][l][r1][r2] (bf16)
// 4 waves per block cover r1base..r1base+3 of one (variant, bi). Output is
// LDS-transposed so the global drain writes 256B-contiguous runs per l
// (vs 32 scattered 64B chunks at 2KB stride per wave before).
__global__ __launch_bounds__(256) void k_attn(const float* __restrict__ yh_in, const float* __restrict__ yw_in,
                       const float* __restrict__ W2h, const float* __restrict__ b2h,
                       const float* __restrict__ W2w, const float* __restrict__ b2w,
                       bf16* __restrict__ attn_h, bf16* __restrict__ attn_w) {
    __shared__ bf16 Ls[32 * 136];         // [l][4*32 + 8 pad]  8.5 KB
    int bx = blockIdx.x;                  // 0..1023
    const float* yproj; const float* W2; const float* b2; bf16* attn;
    int blk0;
    if (bx < 512) { yproj = yh_in; W2 = W2h; b2 = b2h; attn = attn_h; blk0 = bx * 4; }
    else          { yproj = yw_in; W2 = W2w; b2 = b2w; attn = attn_w; blk0 = (bx - 512) * 4; }
    int bi = blk0 >> 5, r1base = blk0 & 31;
    int wv = threadIdx.x >> 6;
    int r1 = r1base + wv;
    int g = r1 >> 2;
    int cb = g * 8;
    int e = cb >> 5, rb = cb & 31;        // 8 consecutive rows of plane e
    int lane = threadIdx.x & 63;
    int l = lane & 31, half = lane >> 5;
    float yv[8];
    const float* ybase = yproj + (((bi * 2 + e) * 32 + rb) * 32 + l);
#pragma unroll
    for (int c = 0; c < 8; ++c) yv[c] = ybase[c * 32];
    float z[16];
#pragma unroll
    for (int jj = 0; jj < 16; ++jj) {
        int r2 = half * 16 + jj;
        int row = r1 * 32 + r2;
        const float4* wp = (const float4*)(W2 + (size_t)row * 8);
        float4 wa = wp[0], wb = wp[1];
        z[jj] = b2[row]
              + yv[0]*wa.x + yv[1]*wa.y + yv[2]*wa.z + yv[3]*wa.w
              + yv[4]*wb.x + yv[5]*wb.y + yv[6]*wb.z + yv[7]*wb.w;
    }
    float m = -1e30f;
#pragma unroll
    for (int jj = 0; jj < 16; ++jj) m = fmaxf(m, z[jj]);
    m = fmaxf(m, __shfl_xor(m, 32, 64));
    float s = 0.f;
#pragma unroll
    for (int jj = 0; jj < 16; ++jj) { z[jj] = __expf(z[jj] - m); s += z[jj]; }
    s += __shfl_xor(s, 32, 64);
    float inv = 1.f / s;
    bf16x8 o0, o1;
#pragma unroll
    for (int jj = 0; jj < 8; ++jj) o0[jj] = (bf16)(z[jj] * inv);
#pragma unroll
    for (int jj = 0; jj < 8; ++jj) o1[jj] = (bf16)(z[8 + jj] * inv);
    // fill: lane (l, half) of wave wv holds r2 = half*16 + 0..15 of row (l, r1)
    bf16* lp = Ls + l * 136 + wv * 32 + half * 16;
    *(bf16x8*)lp       = o0;
    *(bf16x8*)(lp + 8) = o1;
    __syncthreads();
    // drain: thread (tl, part) writes 32B at attn[bi][tl][r1base..+3][...] run
    int tl = threadIdx.x >> 3, part = threadIdx.x & 7;
    const bf16* sp = Ls + tl * 136 + part * 16;
    bf16* dst = attn + (((size_t)(bi * 32 + tl) * 32 + r1base) * 32) + part * 16;
    *(bf16x8*)dst       = *(const bf16x8*)sp;
    *(bf16x8*)(dst + 8) = *(const bf16x8*)(sp + 8);
}

// ---------------------------------------------------------------- K3: fused Yh+Yw -> T (bf16, row-major) — r0 proven version
__global__ __launch_bounds__(256) void k_mix(const bf16* __restrict__ x,
                                             const bf16* __restrict__ attn_h,
                                             const bf16* __restrict__ attn_w,
                                             bf16* __restrict__ T) {
    __shared__ bf16 Xs[1024 * 16];      // [pixel][16 cols]  32 KB
    __shared__ bf16 Ts[1024 * 16];      // Yh park           32 KB
    int n = blockIdx.x;                 // 0..1535
    int a = n >> 5, r = n & 31;
    int q = a * 8 + (r & 7);            // 0..383
    int bi = q / 6, cq = q % 6;
    int c = cq * 4 + (r >> 3);          // 0..23
    int dbase = c * 16;
    int tid = threadIdx.x;
    int wv = tid >> 6, lane = tid & 63;
    int n16 = lane & 15, quad = lane >> 4;

    // ---- stage x[bi][:, dbase:dbase+16] -> Xs (lane-linear 16B chunks)
    const char* gbase = (const char*)(x + (size_t)bi * 1024 * 384 + dbase);
#pragma unroll
    for (int it = 0; it < 8; ++it) {
        int p0 = wv * 256 + it * 32;                 // 32 pixels per inst
        const char* g = gbase + (size_t)(p0 + (lane >> 1)) * 768 + (lane & 1) * 16;
        char* l = (char*)Xs + p0 * 32 + lane * 16;
        async_copy16(l, g);
    }
    __syncthreads();

    // ---- phase 1: Yh[h,w,d] = sum_j ah[w,h,j] x[j,w,d] -> Ts
#pragma unroll
    for (int wl = 0; wl < 8; ++wl) {
        int w = wv * 8 + wl;
        const bf16* ab = attn_h + ((size_t)(bi * 32 + w) * 32) * 32;
        bf16x8 af0 = *(const bf16x8*)(ab + n16 * 32 + quad * 8);
        bf16x8 af1 = *(const bf16x8*)(ab + (16 + n16) * 32 + quad * 8);
        bf16x8 bfrag;
#pragma unroll
        for (int i = 0; i < 8; ++i) {
            int j = quad * 8 + i;
            bfrag[i] = Xs[(j * 32 + w) * 16 + n16];
        }
        floatx4 c0 = {0.f, 0.f, 0.f, 0.f}, c1 = {0.f, 0.f, 0.f, 0.f};
        c0 = __builtin_amdgcn_mfma_f32_16x16x32_bf16(af0, bfrag, c0, 0, 0, 0);
        c1 = __builtin_amdgcn_mfma_f32_16x16x32_bf16(af1, bfrag, c1, 0, 0, 0);
#pragma unroll
        for (int rr = 0; rr < 4; ++rr) {
            int h0 = quad * 4 + rr;
            Ts[(h0 * 32 + w) * 16 + n16]        = (bf16)c0[rr];
            Ts[((16 + h0) * 32 + w) * 16 + n16] = (bf16)c1[rr];
        }
    }
    __syncthreads();

    // ---- phase 2: Yw[h,w,d] = sum_j aw[h,w,j] x[h,j,d]; T = Yh + Yw
#pragma unroll
    for (int hl = 0; hl < 8; ++hl) {
        int h = wv * 8 + hl;
        const bf16* ab = attn_w + ((size_t)(bi * 32 + h) * 32) * 32;
        bf16x8 af0 = *(const bf16x8*)(ab + n16 * 32 + quad * 8);
        bf16x8 af1 = *(const bf16x8*)(ab + (16 + n16) * 32 + quad * 8);
        bf16x8 bfrag;
#pragma unroll
        for (int i = 0; i < 8; ++i) {
            int j = quad * 8 + i;
            bfrag[i] = Xs[(h * 32 + j) * 16 + n16];
        }
        floatx4 c0 = {0.f, 0.f, 0.f, 0.f}, c1 = {0.f, 0.f, 0.f, 0.f};
        c0 = __builtin_amdgcn_mfma_f32_16x16x32_bf16(af0, bfrag, c0, 0, 0, 0);
        c1 = __builtin_amdgcn_mfma_f32_16x16x32_bf16(af1, bfrag, c1, 0, 0, 0);
        bf16* Tr = T + ((size_t)(bi * 32 + h) * 32) * 384 + dbase;
#pragma unroll
        for (int rr = 0; rr < 4; ++rr) {
            int w0 = quad * 4 + rr;
            Tr[(size_t)w0 * 384 + n16] =
                (bf16)(c0[rr] + (float)Ts[(h * 32 + w0) * 16 + n16]);
            Tr[(size_t)(16 + w0) * 384 + n16] =
                (bf16)(c1[rr] + (float)Ts[(h * 32 + 16 + w0) * 16 + n16]);
        }
    }
}

// ---------------------------------------------------------------- K5: out = [T|xb] @ Wfull^T + bco   (M=65536,N=384,K=768), out fp32
// r4 proven winner (62.4-64.4 us): reg-staged, LDP=72 padded LDS,
// 2 barriers/K-step, T14 issue-early/write-late ping-pong. DO NOT TOUCH.
#define LDP 72
__global__ __launch_bounds__(256) void k_gemm(const bf16* __restrict__ T, const bf16* __restrict__ x,
                                              const bf16* __restrict__ Wfull, const float* __restrict__ bco,
                                              float* __restrict__ out) {
    __shared__ bf16 As[128 * LDP];
    __shared__ bf16 Bs[128 * LDP];
    int bx = blockIdx.x;               // 0..1535
    int gid = (bx & 7) * 192 + (bx >> 3);
    int nt = gid % 3, pt = gid / 3;
    int obase = nt * 128;
    int pbase = pt * 128;
    int tid = threadIdx.x;
    int wv = tid >> 6, lane = tid & 63;
    int wm = wv & 1, wn = wv >> 1;
    int n16 = lane & 15, quad = lane >> 4;
    int lrow = tid >> 3;           // 0..31
    int lchunk = tid & 7;          // 0..7
    floatx4 zero = {0.f, 0.f, 0.f, 0.f};
    floatx4 acc[4][4];
#pragma unroll
    for (int i = 0; i < 4; ++i)
#pragma unroll
        for (int j = 0; j < 4; ++j) acc[i][j] = zero;

    const bf16* Bg0 = Wfull + (size_t)obase * 768;

    auto load_tile = [&](int kt, bf16x8 (&av)[4], bf16x8 (&bv)[4]) {
        const bf16* Asrc = (kt < 6) ? (T + (size_t)pbase * 384 + kt * 64)
                                    : (x + (size_t)pbase * 384 + (kt - 6) * 64);
        const bf16* Bsrc = Bg0 + kt * 64;
#pragma unroll
        for (int s = 0; s < 4; ++s)
            av[s] = *(const bf16x8*)(Asrc + (size_t)(s * 32 + lrow) * 384 + lchunk * 8);
#pragma unroll
        for (int s = 0; s < 4; ++s)
            bv[s] = *(const bf16x8*)(Bsrc + (size_t)(s * 32 + lrow) * 768 + lchunk * 8);
    };

    auto step = [&](int kt, bf16x8 (&av)[4], bf16x8 (&bv)[4],
                    bf16x8 (&nav)[4], bf16x8 (&nbv)[4]) {
        __syncthreads();           // previous iteration's LDS reads done
#pragma unroll
        for (int s = 0; s < 4; ++s)
            *(bf16x8*)(As + (s * 32 + lrow) * LDP + lchunk * 8) = av[s];
#pragma unroll
        for (int s = 0; s < 4; ++s)
            *(bf16x8*)(Bs + (s * 32 + lrow) * LDP + lchunk * 8) = bv[s];
        __syncthreads();
        if (kt < 11) load_tile(kt + 1, nav, nbv);   // issue; consumed next step
#pragma unroll
        for (int ks = 0; ks < 2; ++ks) {
            bf16x8 a[4], b[4];
#pragma unroll
            for (int i = 0; i < 4; ++i)
                a[i] = *(const bf16x8*)(As + (wm * 64 + i * 16 + n16) * LDP + ks * 32 + quad * 8);
#pragma unroll
            for (int i = 0; i < 4; ++i)
                b[i] = *(const bf16x8*)(Bs + (wn * 64 + i * 16 + n16) * LDP + ks * 32 + quad * 8);
#pragma unroll
            for (int i = 0; i < 4; ++i)
#pragma unroll
                for (int j = 0; j < 4; ++j)
                    acc[i][j] = __builtin_amdgcn_mfma_f32_16x16x32_bf16(a[i], b[j], acc[i][j], 0, 0, 0);
        }
    };

    bf16x8 avA[4], bvA[4], avB[4], bvB[4];
    load_tile(0, avA, bvA);
    for (int kt = 0; kt < 12; kt += 2) {
        step(kt,     avA, bvA, avB, bvB);
        step(kt + 1, avB, bvB, avA, bvA);
    }

    // epilogue: fp32 output
#pragma unroll
    for (int j = 0; j < 4; ++j) {
        int o = obase + wn * 64 + j * 16 + n16;
        float bcv = bco[o];
#pragma unroll
        for (int i = 0; i < 4; ++i) {
            int prow = pbase + wm * 64 + i * 16 + quad * 4;
#pragma unroll
            for (int r = 0; r < 4; ++r)
                out[(size_t)(prow + r) * 384 + o] = acc[i][j][r] + bcv;
        }
    }
}

// ---------------------------------------------------------------- launch
extern "C" void kernel_launch(void* const* d_in, const int* in_sizes, int n_in,
                              void* d_out, int out_size, void* d_ws, size_t ws_size,
                              hipStream_t stream) {
    const float* x   = (const float*)d_in[0];
    const float* Wc  = (const float*)d_in[1];
    const float* bc  = (const float*)d_in[2];
    const float* Wo  = (const float*)d_in[3];
    const float* bo  = (const float*)d_in[4];
    const float* W1h = (const float*)d_in[5];
    const float* b1h = (const float*)d_in[6];
    const float* W2h = (const float*)d_in[7];
    const float* b2h = (const float*)d_in[8];
    const float* W1w = (const float*)d_in[9];
    const float* b1w = (const float*)d_in[10];
    const float* W2w = (const float*)d_in[11];
    const float* b2w = (const float*)d_in[12];
    float* out = (float*)d_out;

    char* ws = (char*)d_ws;
    size_t off = 0;
    auto alloc = [&](size_t bytes) {
        void* p = ws + off;
        off = (off + bytes + 255) & ~(size_t)255;
        return p;
    };
    bf16*  xb     = (bf16*)alloc((size_t)NPIX * 384 * 2);  // bf16 copy of x, row-major
    float* yh     = (float*)alloc((size_t)131072 * 4);     // [B][2][32][32]
    float* yw     = (float*)alloc((size_t)131072 * 4);
    bf16*  attn_h = (bf16*)alloc((size_t)2097152 * 2);     // [B][W][H][H]
    bf16*  attn_w = (bf16*)alloc((size_t)2097152 * 2);     // [B][H][W][W]
    bf16*  T      = (bf16*)alloc((size_t)NPIX * 384 * 2);  // Yh+Yw, row-major
    bf16*  Wfull  = (bf16*)alloc((size_t)384 * 768 * 2);   // [Wo | Wo@Wc]
    float* bco    = (float*)alloc((size_t)384 * 4);

    hipLaunchKernelGGL(k_proj, dim3(2048 + 769), dim3(256), 0, stream,
                       x, xb, W1h, b1h, W1w, b1w, yh, yw,
                       Wc, bc, Wo, bo, Wfull, bco);
    hipLaunchKernelGGL(k_attn, dim3(1024), dim3(256), 0, stream, yh, yw, W2h, b2h, W2w, b2w, attn_h, attn_w);
    hipLaunchKernelGGL(k_mix, dim3(1536), dim3(256), 0, stream, xb, attn_h, attn_w, T);
    hipLaunchKernelGGL(k_gemm, dim3(1536), dim3(256), 0, stream, T, xb, Wfull, bco, out);
}